// Round 6
// baseline (451.615 us; speedup 1.0000x reference)
//
#include <hip/hip_runtime.h>

#define NN 50000
#define NE 800000
#define DD 128
#define D4 32       // float4s per row
#define SCAN_NB 196 // ceil(NN/256)

typedef __attribute__((ext_vector_type(8))) short short8;
typedef __attribute__((ext_vector_type(4))) float f32x4;

__device__ __forceinline__ unsigned short f2bf(float f) {
    unsigned u = __float_as_uint(f);
    unsigned r = u + 0x7FFF + ((u >> 16) & 1);  // RTN-even
    return (unsigned short)(r >> 16);
}
__device__ __forceinline__ float bf2f(unsigned short s) {
    return __uint_as_float(((unsigned)s) << 16);
}

// ---------------- elementwise helpers ----------------

__global__ void zero_int(int* __restrict__ p, int n) {
    int i = blockIdx.x * blockDim.x + threadIdx.x;
    if (i < n) p[i] = 0;
}

// xb = bf16(x_in)
__global__ void x2b(const float4* __restrict__ xin, ushort4* __restrict__ xb) {
    int i = blockIdx.x * blockDim.x + threadIdx.x;
    if (i >= NN * D4) return;
    float4 v = xin[i];
    ushort4 o;
    o.x = f2bf(v.x); o.y = f2bf(v.y); o.z = f2bf(v.z); o.w = f2bf(v.w);
    xb[i] = o;
}

// ---------------- weight prep: Wt[m][n][k] = bf16(W[m][k][n]) ----------------

__global__ void prep_wt(const float* __restrict__ W1, const float* __restrict__ W2,
                        unsigned short* __restrict__ Wt) {
    int i = blockIdx.x * blockDim.x + threadIdx.x;
    if (i >= 6 * 16384) return;
    int m = i >> 14;
    int r = i & 16383;
    int n = r >> 7;
    int k = r & 127;
    const float* Ws = (m < 3) ? (W1 + m * 16384) : (W2 + (m - 3) * 16384);
    Wt[i] = f2bf(Ws[k * 128 + n]);
}

// ---------------- CSR build ----------------

__global__ void hist_kernel(const int* __restrict__ ei, int* __restrict__ counts) {
    int e = blockIdx.x * blockDim.x + threadIdx.x;
    if (e < NE) atomicAdd(&counts[ei[NE + e]], 1);
}

__global__ void block_sums(const int* __restrict__ counts, int* __restrict__ bsum) {
    int i = blockIdx.x * 256 + threadIdx.x;
    int v = (i < NN) ? counts[i] : 0;
#pragma unroll
    for (int off = 1; off < 64; off <<= 1) v += __shfl_xor(v, off);
    __shared__ int wsum[4];
    if ((threadIdx.x & 63) == 0) wsum[threadIdx.x >> 6] = v;
    __syncthreads();
    if (threadIdx.x == 0) bsum[blockIdx.x] = wsum[0] + wsum[1] + wsum[2] + wsum[3];
}

__global__ void scan_bsums(const int* __restrict__ bsum, int* __restrict__ bbase) {
    __shared__ int sh[256];
    int tid = threadIdx.x;
    sh[tid] = (tid < SCAN_NB) ? bsum[tid] : 0;
    __syncthreads();
    for (int off = 1; off < 256; off <<= 1) {
        int add = (tid >= off) ? sh[tid - off] : 0;
        __syncthreads();
        sh[tid] += add;
        __syncthreads();
    }
    if (tid < SCAN_NB) bbase[tid] = (tid == 0) ? 0 : sh[tid - 1];
}

__global__ void rowptr_fill(const int* __restrict__ counts, const int* __restrict__ bbase,
                            int* __restrict__ rowptr, int* __restrict__ cursor) {
    __shared__ int sh[256];
    int tid = threadIdx.x;
    int i = blockIdx.x * 256 + tid;
    int c = (i < NN) ? counts[i] : 0;
    sh[tid] = c;
    __syncthreads();
    for (int off = 1; off < 256; off <<= 1) {
        int add = (tid >= off) ? sh[tid - off] : 0;
        __syncthreads();
        sh[tid] += add;
        __syncthreads();
    }
    int excl = bbase[blockIdx.x] + sh[tid] - c;
    if (i < NN) {
        rowptr[i] = excl;
        cursor[i] = excl;
        if (i == NN - 1) rowptr[NN] = excl + c;  // == NE
    }
}

// srcw[idx] = (src << 16) | bf16(w)   -- 4 B/edge: halves the scattered-write
// line footprint (3.2 MB < 4 MB per-XCD L2) so stores merge before eviction.
__global__ void fill_kernel(const int* __restrict__ ei, const float* __restrict__ ew,
                            int* __restrict__ cursor, unsigned* __restrict__ srcw) {
    int e = blockIdx.x * blockDim.x + threadIdx.x;
    if (e >= NE) return;
    int dst = ei[NE + e];
    int idx = atomicAdd(&cursor[dst], 1);
    srcw[idx] = (((unsigned)ei[e]) << 16) | (unsigned)f2bf(ew[e]);
}

// ---- gather + GIN combine: g[n] = bf16((1+eps)*xb[n] + sum_e w_e * xb[src_e]) ----
// 32 lanes per node (8 B of bf16 row each), 8 nodes per 256-block. Zeroes BN stats.

__global__ void __launch_bounds__(256) gather_kernel(
    const unsigned short* __restrict__ xb, const unsigned* __restrict__ srcw,
    const int* __restrict__ rowptr, const float* __restrict__ epsp,
    unsigned short* __restrict__ g, float* __restrict__ stats) {
    if (blockIdx.x == 0) stats[threadIdx.x] = 0.f;  // 256 floats: sum | sumsq
    int node = blockIdx.x * 8 + (threadIdx.x >> 5);
    int lane = threadIdx.x & 31;
    if (node >= NN) return;
    float epsv = 1.0f + *epsp;
    int beg = rowptr[node], end = rowptr[node + 1];
    const ushort4* xb4 = (const ushort4*)xb;
    ushort4 xv = xb4[node * D4 + lane];
    float4 acc = make_float4(bf2f(xv.x) * epsv, bf2f(xv.y) * epsv,
                             bf2f(xv.z) * epsv, bf2f(xv.w) * epsv);
    int i = beg;
    for (; i + 1 < end; i += 2) {
        unsigned sw0 = srcw[i];
        unsigned sw1 = srcw[i + 1];
        ushort4 r0 = xb4[(sw0 >> 16) * D4 + lane];
        ushort4 r1 = xb4[(sw1 >> 16) * D4 + lane];
        float w0 = bf2f((unsigned short)(sw0 & 0xffff));
        float w1 = bf2f((unsigned short)(sw1 & 0xffff));
        acc.x += bf2f(r0.x) * w0; acc.y += bf2f(r0.y) * w0;
        acc.z += bf2f(r0.z) * w0; acc.w += bf2f(r0.w) * w0;
        acc.x += bf2f(r1.x) * w1; acc.y += bf2f(r1.y) * w1;
        acc.z += bf2f(r1.z) * w1; acc.w += bf2f(r1.w) * w1;
    }
    if (i < end) {
        unsigned sw = srcw[i];
        ushort4 r = xb4[(sw >> 16) * D4 + lane];
        float w = bf2f((unsigned short)(sw & 0xffff));
        acc.x += bf2f(r.x) * w; acc.y += bf2f(r.y) * w;
        acc.z += bf2f(r.z) * w; acc.w += bf2f(r.w) * w;
    }
    ushort4 o;
    o.x = f2bf(acc.x); o.y = f2bf(acc.y); o.z = f2bf(acc.z); o.w = f2bf(acc.w);
    ((ushort4*)g)[node * D4 + lane] = o;
}

// ---------------- MFMA GEMM: 64 rows x 128 cols per block, 4 waves ----------------
// grid = 782 (~3 blocks/CU): R5's 128-row tile gave only 1.5 blocks/CU -> no
// inter-block latency hiding. Wave w owns cols [w*32, w*32+32); B-frags in regs.
// MODE 0: out = bf16(relu(A@Wt^T + b))                        (t)
// MODE 1: out = bf16(A@Wt^T + b), BN col sums/sumsq -> stats  (h)

#define GM 64  // rows per block

template <int MODE>
__global__ void __launch_bounds__(256) mfma_gemm(
    const unsigned short* __restrict__ A,   // M x 128 bf16 row-major
    const unsigned short* __restrict__ Wt,  // 128 x 128 bf16, [n][k]
    const float* __restrict__ bias,
    unsigned short* __restrict__ outB, float* __restrict__ stats) {
    __shared__ unsigned short As[GM * 128];  // 16 KB

    int tid = threadIdx.x;
    int wave = tid >> 6;
    int lane = tid & 63;
    int q = lane >> 4;    // quad 0..3
    int ml = lane & 15;
    int r0 = blockIdx.x * GM;

    // stage A tile (zero-pad rows >= NN), 16B-chunk XOR swizzle
#pragma unroll
    for (int i = 0; i < GM / 16; i++) {
        int idx = i * 256 + tid;  // chunk id
        int row = idx >> 4;
        int c = idx & 15;
        float4 v = make_float4(0.f, 0.f, 0.f, 0.f);
        int grow = r0 + row;
        if (grow < NN) v = *(const float4*)(A + grow * DD + c * 8);
        int cs = c ^ (row & 15);
        *(float4*)(&As[row * DD + cs * 8]) = v;
    }

    // B fragments from global (32 KB, L2-resident)
    short8 Bf[2][4];
#pragma unroll
    for (int t = 0; t < 2; t++)
#pragma unroll
        for (int ks = 0; ks < 4; ks++) {
            int n = wave * 32 + t * 16 + ml;
            Bf[t][ks] = *(const short8*)(Wt + n * DD + ks * 32 + q * 8);
        }

    float bvl[2] = {bias[wave * 32 + ml], bias[wave * 32 + 16 + ml]};

    __syncthreads();

    float s[2] = {0.f, 0.f}, s2[2] = {0.f, 0.f};

    for (int rt = 0; rt < GM / 16; rt++) {
        int arow = rt * 16 + ml;
        short8 Af[4];
#pragma unroll
        for (int ks = 0; ks < 4; ks++) {
            int cs = (ks * 4 + q) ^ (arow & 15);
            Af[ks] = *(const short8*)(&As[arow * DD + cs * 8]);
        }
        f32x4 acc[2] = {{0.f, 0.f, 0.f, 0.f}, {0.f, 0.f, 0.f, 0.f}};
#pragma unroll
        for (int ks = 0; ks < 4; ks++) {
            acc[0] = __builtin_amdgcn_mfma_f32_16x16x32_bf16(Af[ks], Bf[0][ks], acc[0], 0, 0, 0);
            acc[1] = __builtin_amdgcn_mfma_f32_16x16x32_bf16(Af[ks], Bf[1][ks], acc[1], 0, 0, 0);
        }
        // epilogue: C/D layout col=lane&15, row=quad*4+reg  [m89-verified]
#pragma unroll
        for (int t = 0; t < 2; t++) {
            int col = wave * 32 + t * 16 + ml;
#pragma unroll
            for (int r = 0; r < 4; r++) {
                int grow = r0 + rt * 16 + q * 4 + r;
                if (grow < NN) {
                    float v = acc[t][r] + bvl[t];
                    if (MODE == 0) {
                        outB[grow * DD + col] = f2bf(fmaxf(v, 0.f));
                    } else {
                        outB[grow * DD + col] = f2bf(v);
                        s[t] += v;
                        s2[t] += v * v;
                    }
                }
            }
        }
    }

    if (MODE == 1) {
#pragma unroll
        for (int t = 0; t < 2; t++) {
            float a = s[t], b = s2[t];
            a += __shfl_xor(a, 16); b += __shfl_xor(b, 16);
            a += __shfl_xor(a, 32); b += __shfl_xor(b, 32);
            if (q == 0) {
                int col = wave * 32 + t * 16 + ml;
                atomicAdd(&stats[col], a);
                atomicAdd(&stats[DD + col], b);
            }
        }
    }
}

// -------- BN apply + ReLU + residual (bf16 chain):
//   xb_out = bf16(xb_in + relu(bn(hb)));  last layer also writes fp32 x. --------

__global__ void bn_apply(const unsigned short* __restrict__ hb, const float* __restrict__ stats,
                         const float* __restrict__ gamma, const float* __restrict__ beta,
                         const unsigned short* __restrict__ xbin, ushort4* __restrict__ xbout,
                         float4* __restrict__ xf32) {
    int i = blockIdx.x * blockDim.x + threadIdx.x;
    if (i >= NN * D4) return;
    int c4 = i & 31;
    const float invN = 1.0f / NN;
    float4 s = ((const float4*)stats)[c4];
    float4 s2 = ((const float4*)stats)[D4 + c4];
    float4 mu = make_float4(s.x * invN, s.y * invN, s.z * invN, s.w * invN);
    float4 var = make_float4(s2.x * invN - mu.x * mu.x, s2.y * invN - mu.y * mu.y,
                             s2.z * invN - mu.z * mu.z, s2.w * invN - mu.w * mu.w);
    float4 inv = make_float4(rsqrtf(var.x + 1e-5f), rsqrtf(var.y + 1e-5f),
                             rsqrtf(var.z + 1e-5f), rsqrtf(var.w + 1e-5f));
    float4 g = ((const float4*)gamma)[c4];
    float4 b = ((const float4*)beta)[c4];
    ushort4 hu = ((const ushort4*)hb)[i];
    float4 hv = make_float4(bf2f(hu.x), bf2f(hu.y), bf2f(hu.z), bf2f(hu.w));
    ushort4 xu = ((const ushort4*)xbin)[i];
    float4 xv = make_float4(bf2f(xu.x), bf2f(xu.y), bf2f(xu.z), bf2f(xu.w));
    float4 v = make_float4(fmaxf(g.x * (hv.x - mu.x) * inv.x + b.x, 0.f),
                           fmaxf(g.y * (hv.y - mu.y) * inv.y + b.y, 0.f),
                           fmaxf(g.z * (hv.z - mu.z) * inv.z + b.z, 0.f),
                           fmaxf(g.w * (hv.w - mu.w) * inv.w + b.w, 0.f));
    float4 o = make_float4(xv.x + v.x, xv.y + v.y, xv.z + v.z, xv.w + v.w);
    if (xbout) {
        ushort4 ob;
        ob.x = f2bf(o.x); ob.y = f2bf(o.y); ob.z = f2bf(o.z); ob.w = f2bf(o.w);
        xbout[i] = ob;
    }
    if (xf32) xf32[i] = o;
}

// ---------------- launcher ----------------

extern "C" void kernel_launch(void* const* d_in, const int* in_sizes, int n_in,
                              void* d_out, int out_size, void* d_ws, size_t ws_size,
                              hipStream_t stream) {
    const float* x_in = (const float*)d_in[0];
    const int* ei = (const int*)d_in[1];
    // d_in[2] = edge_attr (unused)
    const float* ew = (const float*)d_in[3];
    const float* W1 = (const float*)d_in[4];
    const float* b1 = (const float*)d_in[5];
    const float* W2 = (const float*)d_in[6];
    const float* b2 = (const float*)d_in[7];
    const float* eps = (const float*)d_in[8];
    const float* gamma = (const float*)d_in[9];
    const float* beta = (const float*)d_in[10];

    float* x = (float*)d_out;  // final fp32 output

    char* ws = (char*)d_ws;
    unsigned short* g = (unsigned short*)ws;               // GIN input bf16 (12.8 MB)
    unsigned short* t = (unsigned short*)(ws + 12800000);  // MLP mid bf16   (12.8 MB)
    unsigned short* hb = (unsigned short*)(ws + 25600000); // MLP out bf16   (12.8 MB)
    unsigned short* xb = (unsigned short*)(ws + 38400000); // running x bf16 (12.8 MB)
    float* stats = (float*)(ws + 51200000);                // 256 floats (sum | sumsq)
    int* rowptr = (int*)(ws + 51201024);                   // 50001 ints
    int* cursor = (int*)(ws + 51401056);                   // 50000 ints
    int* counts = (int*)(ws + 51601056);                   // 50000 ints; overlaid by Wt after scan
    unsigned short* Wtall = (unsigned short*)(ws + 51601056);  // 6*16384 bf16
    unsigned* srcw = (unsigned*)(ws + 51801056);           // 800000 uint (src<<16 | bf16 w)
    int* bsum = (int*)(ws + 55001056);                     // 196 ints
    int* bbase = (int*)(ws + 55002080);                    // 196 ints

    const int n4x = NN * D4;

    // ---- CSR build (graph static across layers) ----
    zero_int<<<(NN + 255) / 256, 256, 0, stream>>>(counts, NN);
    hist_kernel<<<(NE + 255) / 256, 256, 0, stream>>>(ei, counts);
    block_sums<<<SCAN_NB, 256, 0, stream>>>(counts, bsum);
    scan_bsums<<<1, 256, 0, stream>>>(bsum, bbase);
    rowptr_fill<<<SCAN_NB, 256, 0, stream>>>(counts, bbase, rowptr, cursor);
    fill_kernel<<<(NE + 255) / 256, 256, 0, stream>>>(ei, ew, cursor, srcw);

    // weights -> bf16 transposed (after scan: Wtall overlays counts)
    prep_wt<<<(6 * 16384 + 255) / 256, 256, 0, stream>>>(W1, W2, Wtall);

    // bf16 mirror of x for layer-0
    x2b<<<(n4x + 255) / 256, 256, 0, stream>>>((const float4*)x_in, (ushort4*)xb);

    const int gemmGrid = (NN + GM - 1) / GM;  // 782

    for (int i = 0; i < 3; i++) {
        const float* b1i = b1 + i * DD;
        const float* b2i = b2 + i * DD;
        const unsigned short* Wt1 = Wtall + i * 16384;
        const unsigned short* Wt2 = Wtall + (3 + i) * 16384;

        // g = bf16((1+eps)*xb + sum w*xb[src]); zeroes stats
        gather_kernel<<<(NN + 7) / 8, 256, 0, stream>>>(xb, srcw, rowptr, eps + i, g, stats);

        // t = bf16(relu(g @ W1 + b1))
        mfma_gemm<0><<<gemmGrid, 256, 0, stream>>>(g, Wt1, b1i, t, nullptr);

        // hb = bf16(t @ W2 + b2), + BN stats (fp32)
        mfma_gemm<1><<<gemmGrid, 256, 0, stream>>>(t, Wt2, b2i, hb, stats);

        // xb = bf16(xb + relu(bn(hb))); layer 2 also writes fp32 x
        bn_apply<<<(n4x + 255) / 256, 256, 0, stream>>>(
            hb, stats, gamma + i * DD, beta + i * DD, xb,
            (i < 2) ? (ushort4*)xb : nullptr,
            (i == 2) ? (float4*)x : nullptr);
    }
}

// Round 7
// 412.671 us; speedup vs baseline: 1.0944x; 1.0944x over previous
//
#include <hip/hip_runtime.h>

#define NN 50000
#define NE 800000
#define DD 128
#define D4 32        // float4s per row
#define NBUCK 196    // ceil(NN/256) node buckets
#define CAP 5120     // staging capacity per bucket (mean 4082, 16 sigma headroom)
#define BIN_EDGES 8192

typedef __attribute__((ext_vector_type(8))) short short8;
typedef __attribute__((ext_vector_type(4))) float f32x4;

__device__ __forceinline__ unsigned short f2bf(float f) {
    unsigned u = __float_as_uint(f);
    unsigned r = u + 0x7FFF + ((u >> 16) & 1);  // RTN-even
    return (unsigned short)(r >> 16);
}
__device__ __forceinline__ float bf2f(unsigned short s) {
    return __uint_as_float(((unsigned)s) << 16);
}

// ---------------- elementwise helpers ----------------

// xb = bf16(x_in)
__global__ void x2b(const float4* __restrict__ xin, ushort4* __restrict__ xb) {
    int i = blockIdx.x * blockDim.x + threadIdx.x;
    if (i >= NN * D4) return;
    float4 v = xin[i];
    ushort4 o;
    o.x = f2bf(v.x); o.y = f2bf(v.y); o.z = f2bf(v.z); o.w = f2bf(v.w);
    xb[i] = o;
}

// ---------------- weight prep: Wt[m][n][k] = bf16(W[m][k][n]) ----------------

__global__ void prep_wt(const float* __restrict__ W1, const float* __restrict__ W2,
                        unsigned short* __restrict__ Wt) {
    int i = blockIdx.x * blockDim.x + threadIdx.x;
    if (i >= 6 * 16384) return;
    int m = i >> 14;
    int r = i & 16383;
    int n = r >> 7;
    int k = r & 127;
    const float* Ws = (m < 3) ? (W1 + m * 16384) : (W2 + (m - 3) * 16384);
    Wt[i] = f2bf(Ws[k * 128 + n]);
}

// ---------------- CSR build: LDS-staged counting sort ----------------
// R6 lesson: scattered sub-line global stores cost a full 64B line-writeback
// each (WRITE_SIZE == NE*64B for both 8B and 4B elements). All global writes
// below are coalesced runs flushed from LDS.

__global__ void init_bcur(int* __restrict__ bcur) {
    int t = threadIdx.x;
    if (t < NBUCK) bcur[t] = t * CAP;
}

// pass A: bin edges into 196 node-buckets (dst>>8), staging bucket-major.
__global__ void __launch_bounds__(256) bin_pass(const int* __restrict__ ei,
                                                const float* __restrict__ ew,
                                                int* __restrict__ bcur,
                                                int2* __restrict__ staging) {
    __shared__ int cnt[256], off[256], cur[256], gb[256];
    __shared__ int2 bin[BIN_EDGES];  // 64 KB
    int tid = threadIdx.x;
    int e0 = blockIdx.x * BIN_EDGES;
    int ne = NE - e0; if (ne > BIN_EDGES) ne = BIN_EDGES;
    cnt[tid] = 0;
    __syncthreads();
    // count
    for (int i = tid; i < ne; i += 256) {
        int dst = ei[NE + e0 + i];
        atomicAdd(&cnt[dst >> 8], 1);
    }
    __syncthreads();
    // inclusive scan cnt -> off
    off[tid] = cnt[tid];
    __syncthreads();
    for (int o = 1; o < 256; o <<= 1) {
        int v = off[tid];
        int add = (tid >= o) ? off[tid - o] : 0;
        __syncthreads();
        off[tid] = v + add;
        __syncthreads();
    }
    cur[tid] = off[tid] - cnt[tid];  // exclusive
    __syncthreads();
    // place into LDS bucket-major
    for (int i = tid; i < ne; i += 256) {
        int e = e0 + i;
        int dst = ei[NE + e];
        unsigned pack = (((unsigned)ei[e]) << 16) | (unsigned)f2bf(ew[e]);
        int p = atomicAdd(&cur[dst >> 8], 1);
        bin[p] = make_int2((int)pack, dst & 255);
    }
    __syncthreads();
    // reserve global staging ranges (1 atomic per bucket per block)
    if (tid < NBUCK) gb[tid] = atomicAdd(&bcur[tid], cnt[tid]);
    __syncthreads();
    // flush: contiguous run per bucket -> mostly full-line stores
    for (int i = tid; i < ne; i += 256) {
        // first b with off[b] > i  (off inclusive; off[NBUCK-1] == ne)
        int lo = 0, hi = NBUCK - 1;
        while (lo < hi) {
            int mid = (lo + hi) >> 1;
            if (off[mid] > i) hi = mid; else lo = mid + 1;
        }
        int local = i - (off[lo] - cnt[lo]);
        staging[gb[lo] + local] = bin[i];
    }
}

// exclusive scan of bucket counts -> bucket bases in final CSR
__global__ void scan_buckets(const int* __restrict__ bcur, int* __restrict__ bb2) {
    __shared__ int sh[256];
    int tid = threadIdx.x;
    int c = (tid < NBUCK) ? (bcur[tid] - tid * CAP) : 0;
    sh[tid] = c;
    __syncthreads();
    for (int o = 1; o < 256; o <<= 1) {
        int v = sh[tid];
        int add = (tid >= o) ? sh[tid - o] : 0;
        __syncthreads();
        sh[tid] += 0;  // keep structure simple
        sh[tid] = v + add;
        __syncthreads();
    }
    if (tid < NBUCK) bb2[tid] = sh[tid] - c;
}

// pass B: one bucket per block; fine-place by dst into LDS, emit rowptr + srcw coalesced.
__global__ void __launch_bounds__(256) place_pass(const int2* __restrict__ staging,
                                                  const int* __restrict__ bcur,
                                                  const int* __restrict__ bb2,
                                                  int* __restrict__ rowptr,
                                                  unsigned* __restrict__ srcw) {
    __shared__ int hist[256], off[256], cur[256];
    __shared__ unsigned outb[CAP];  // 20 KB
    int b = blockIdx.x;
    int tid = threadIdx.x;
    int sbase = b * CAP;
    int nb = bcur[b] - sbase;
    int bucketBase = bb2[b];
    hist[tid] = 0;
    __syncthreads();
    for (int i = tid; i < nb; i += 256) atomicAdd(&hist[staging[sbase + i].y], 1);
    __syncthreads();
    off[tid] = hist[tid];
    __syncthreads();
    for (int o = 1; o < 256; o <<= 1) {
        int v = off[tid];
        int add = (tid >= o) ? off[tid - o] : 0;
        __syncthreads();
        off[tid] = v + add;
        __syncthreads();
    }
    int excl = off[tid] - hist[tid];
    cur[tid] = excl;
    int node = b * 256 + tid;
    if (node < NN) rowptr[node] = bucketBase + excl;
    if (b == 0 && tid == 0) rowptr[NN] = NE;
    __syncthreads();
    for (int i = tid; i < nb; i += 256) {
        int2 r = staging[sbase + i];
        int p = atomicAdd(&cur[r.y], 1);
        outb[p] = (unsigned)r.x;
    }
    __syncthreads();
    for (int i = tid; i < nb; i += 256) srcw[bucketBase + i] = outb[i];
}

// ---- gather + GIN combine: g[n] = bf16((1+eps)*xb[n] + sum_e w_e * xb[src_e]) ----
// 32 lanes per node (8 B of bf16 row each), 8 nodes per 256-block. Zeroes BN stats.

__global__ void __launch_bounds__(256) gather_kernel(
    const unsigned short* __restrict__ xb, const unsigned* __restrict__ srcw,
    const int* __restrict__ rowptr, const float* __restrict__ epsp,
    unsigned short* __restrict__ g, float* __restrict__ stats) {
    if (blockIdx.x == 0) stats[threadIdx.x] = 0.f;  // 256 floats: sum | sumsq
    int node = blockIdx.x * 8 + (threadIdx.x >> 5);
    int lane = threadIdx.x & 31;
    if (node >= NN) return;
    float epsv = 1.0f + *epsp;
    int beg = rowptr[node], end = rowptr[node + 1];
    const ushort4* xb4 = (const ushort4*)xb;
    ushort4 xv = xb4[node * D4 + lane];
    float4 acc = make_float4(bf2f(xv.x) * epsv, bf2f(xv.y) * epsv,
                             bf2f(xv.z) * epsv, bf2f(xv.w) * epsv);
    int i = beg;
    for (; i + 1 < end; i += 2) {
        unsigned sw0 = srcw[i];
        unsigned sw1 = srcw[i + 1];
        ushort4 r0 = xb4[(sw0 >> 16) * D4 + lane];
        ushort4 r1 = xb4[(sw1 >> 16) * D4 + lane];
        float w0 = bf2f((unsigned short)(sw0 & 0xffff));
        float w1 = bf2f((unsigned short)(sw1 & 0xffff));
        acc.x += bf2f(r0.x) * w0; acc.y += bf2f(r0.y) * w0;
        acc.z += bf2f(r0.z) * w0; acc.w += bf2f(r0.w) * w0;
        acc.x += bf2f(r1.x) * w1; acc.y += bf2f(r1.y) * w1;
        acc.z += bf2f(r1.z) * w1; acc.w += bf2f(r1.w) * w1;
    }
    if (i < end) {
        unsigned sw = srcw[i];
        ushort4 r = xb4[(sw >> 16) * D4 + lane];
        float w = bf2f((unsigned short)(sw & 0xffff));
        acc.x += bf2f(r.x) * w; acc.y += bf2f(r.y) * w;
        acc.z += bf2f(r.z) * w; acc.w += bf2f(r.w) * w;
    }
    ushort4 o;
    o.x = f2bf(acc.x); o.y = f2bf(acc.y); o.z = f2bf(acc.z); o.w = f2bf(acc.w);
    ((ushort4*)g)[node * D4 + lane] = o;
}

// ---------------- MFMA GEMM: 64 rows x 128 cols per block, 4 waves ----------------
// MODE 0: out = bf16(relu(A@Wt^T + b))                        (t)
// MODE 1: out = bf16(A@Wt^T + b), BN col sums/sumsq -> stats  (h)

#define GM 64  // rows per block

template <int MODE>
__global__ void __launch_bounds__(256) mfma_gemm(
    const unsigned short* __restrict__ A,   // M x 128 bf16 row-major
    const unsigned short* __restrict__ Wt,  // 128 x 128 bf16, [n][k]
    const float* __restrict__ bias,
    unsigned short* __restrict__ outB, float* __restrict__ stats) {
    __shared__ unsigned short As[GM * 128];  // 16 KB

    int tid = threadIdx.x;
    int wave = tid >> 6;
    int lane = tid & 63;
    int q = lane >> 4;    // quad 0..3
    int ml = lane & 15;
    int r0 = blockIdx.x * GM;

    // stage A tile (zero-pad rows >= NN), 16B-chunk XOR swizzle
#pragma unroll
    for (int i = 0; i < GM / 16; i++) {
        int idx = i * 256 + tid;
        int row = idx >> 4;
        int c = idx & 15;
        float4 v = make_float4(0.f, 0.f, 0.f, 0.f);
        int grow = r0 + row;
        if (grow < NN) v = *(const float4*)(A + grow * DD + c * 8);
        int cs = c ^ (row & 15);
        *(float4*)(&As[row * DD + cs * 8]) = v;
    }

    // B fragments from global (32 KB, L2-resident)
    short8 Bf[2][4];
#pragma unroll
    for (int t = 0; t < 2; t++)
#pragma unroll
        for (int ks = 0; ks < 4; ks++) {
            int n = wave * 32 + t * 16 + ml;
            Bf[t][ks] = *(const short8*)(Wt + n * DD + ks * 32 + q * 8);
        }

    float bvl[2] = {bias[wave * 32 + ml], bias[wave * 32 + 16 + ml]};

    __syncthreads();

    float s[2] = {0.f, 0.f}, s2[2] = {0.f, 0.f};

    for (int rt = 0; rt < GM / 16; rt++) {
        int arow = rt * 16 + ml;
        short8 Af[4];
#pragma unroll
        for (int ks = 0; ks < 4; ks++) {
            int cs = (ks * 4 + q) ^ (arow & 15);
            Af[ks] = *(const short8*)(&As[arow * DD + cs * 8]);
        }
        f32x4 acc[2] = {{0.f, 0.f, 0.f, 0.f}, {0.f, 0.f, 0.f, 0.f}};
#pragma unroll
        for (int ks = 0; ks < 4; ks++) {
            acc[0] = __builtin_amdgcn_mfma_f32_16x16x32_bf16(Af[ks], Bf[0][ks], acc[0], 0, 0, 0);
            acc[1] = __builtin_amdgcn_mfma_f32_16x16x32_bf16(Af[ks], Bf[1][ks], acc[1], 0, 0, 0);
        }
        // epilogue: C/D layout col=lane&15, row=quad*4+reg  [m89-verified]
#pragma unroll
        for (int t = 0; t < 2; t++) {
            int col = wave * 32 + t * 16 + ml;
#pragma unroll
            for (int r = 0; r < 4; r++) {
                int grow = r0 + rt * 16 + q * 4 + r;
                if (grow < NN) {
                    float v = acc[t][r] + bvl[t];
                    if (MODE == 0) {
                        outB[grow * DD + col] = f2bf(fmaxf(v, 0.f));
                    } else {
                        outB[grow * DD + col] = f2bf(v);
                        s[t] += v;
                        s2[t] += v * v;
                    }
                }
            }
        }
    }

    if (MODE == 1) {
#pragma unroll
        for (int t = 0; t < 2; t++) {
            float a = s[t], b = s2[t];
            a += __shfl_xor(a, 16); b += __shfl_xor(b, 16);
            a += __shfl_xor(a, 32); b += __shfl_xor(b, 32);
            if (q == 0) {
                int col = wave * 32 + t * 16 + ml;
                atomicAdd(&stats[col], a);
                atomicAdd(&stats[DD + col], b);
            }
        }
    }
}

// -------- BN apply + ReLU + residual (bf16 chain):
//   xb_out = bf16(xb_in + relu(bn(hb)));  last layer writes fp32 x. --------

__global__ void bn_apply(const unsigned short* __restrict__ hb, const float* __restrict__ stats,
                         const float* __restrict__ gamma, const float* __restrict__ beta,
                         const unsigned short* __restrict__ xbin, ushort4* __restrict__ xbout,
                         float4* __restrict__ xf32) {
    int i = blockIdx.x * blockDim.x + threadIdx.x;
    if (i >= NN * D4) return;
    int c4 = i & 31;
    const float invN = 1.0f / NN;
    float4 s = ((const float4*)stats)[c4];
    float4 s2 = ((const float4*)stats)[D4 + c4];
    float4 mu = make_float4(s.x * invN, s.y * invN, s.z * invN, s.w * invN);
    float4 var = make_float4(s2.x * invN - mu.x * mu.x, s2.y * invN - mu.y * mu.y,
                             s2.z * invN - mu.z * mu.z, s2.w * invN - mu.w * mu.w);
    float4 inv = make_float4(rsqrtf(var.x + 1e-5f), rsqrtf(var.y + 1e-5f),
                             rsqrtf(var.z + 1e-5f), rsqrtf(var.w + 1e-5f));
    float4 g = ((const float4*)gamma)[c4];
    float4 b = ((const float4*)beta)[c4];
    ushort4 hu = ((const ushort4*)hb)[i];
    float4 hv = make_float4(bf2f(hu.x), bf2f(hu.y), bf2f(hu.z), bf2f(hu.w));
    ushort4 xu = ((const ushort4*)xbin)[i];
    float4 xv = make_float4(bf2f(xu.x), bf2f(xu.y), bf2f(xu.z), bf2f(xu.w));
    float4 v = make_float4(fmaxf(g.x * (hv.x - mu.x) * inv.x + b.x, 0.f),
                           fmaxf(g.y * (hv.y - mu.y) * inv.y + b.y, 0.f),
                           fmaxf(g.z * (hv.z - mu.z) * inv.z + b.z, 0.f),
                           fmaxf(g.w * (hv.w - mu.w) * inv.w + b.w, 0.f));
    float4 o = make_float4(xv.x + v.x, xv.y + v.y, xv.z + v.z, xv.w + v.w);
    if (xbout) {
        ushort4 ob;
        ob.x = f2bf(o.x); ob.y = f2bf(o.y); ob.z = f2bf(o.z); ob.w = f2bf(o.w);
        xbout[i] = ob;
    }
    if (xf32) xf32[i] = o;
}

// ---------------- launcher ----------------

extern "C" void kernel_launch(void* const* d_in, const int* in_sizes, int n_in,
                              void* d_out, int out_size, void* d_ws, size_t ws_size,
                              hipStream_t stream) {
    const float* x_in = (const float*)d_in[0];
    const int* ei = (const int*)d_in[1];
    // d_in[2] = edge_attr (unused)
    const float* ew = (const float*)d_in[3];
    const float* W1 = (const float*)d_in[4];
    const float* b1 = (const float*)d_in[5];
    const float* W2 = (const float*)d_in[6];
    const float* b2 = (const float*)d_in[7];
    const float* eps = (const float*)d_in[8];
    const float* gamma = (const float*)d_in[9];
    const float* beta = (const float*)d_in[10];

    float* x = (float*)d_out;  // final fp32 output

    char* ws = (char*)d_ws;
    unsigned short* g = (unsigned short*)ws;               // GIN input bf16 (12.8 MB)
    unsigned short* t = (unsigned short*)(ws + 12800000);  // MLP mid bf16   (12.8 MB)
    unsigned short* hb = (unsigned short*)(ws + 25600000); // MLP out bf16   (12.8 MB)
    int2* staging = (int2*)(ws + 25600000);                // CSR staging 8.03 MB, overlays hb
                                                           // (dead until gemm2 of layer 0)
    unsigned short* xb = (unsigned short*)(ws + 38400000); // running x bf16 (12.8 MB)
    float* stats = (float*)(ws + 51200000);                // 256 floats (sum | sumsq)
    int* rowptr = (int*)(ws + 51201024);                   // 50001 ints
    unsigned short* Wtall = (unsigned short*)(ws + 51401216);  // 6*16384 bf16 (196,608 B)
    unsigned* srcw = (unsigned*)(ws + 51597824);           // 800000 uint (src<<16 | bf16 w)
    int* bcur = (int*)(ws + 54797824);                     // 196 ints (staging cursors)
    int* bb2 = (int*)(ws + 54798848);                      // 196 ints (bucket CSR bases)

    const int n4x = NN * D4;

    // ---- CSR build: LDS-staged counting sort (all global writes coalesced) ----
    init_bcur<<<1, 256, 0, stream>>>(bcur);
    bin_pass<<<(NE + BIN_EDGES - 1) / BIN_EDGES, 256, 0, stream>>>(ei, ew, bcur, staging);
    scan_buckets<<<1, 256, 0, stream>>>(bcur, bb2);
    place_pass<<<NBUCK, 256, 0, stream>>>(staging, bcur, bb2, rowptr, srcw);

    // weights -> bf16 transposed
    prep_wt<<<(6 * 16384 + 255) / 256, 256, 0, stream>>>(W1, W2, Wtall);

    // bf16 mirror of x for layer-0
    x2b<<<(n4x + 255) / 256, 256, 0, stream>>>((const float4*)x_in, (ushort4*)xb);

    const int gemmGrid = (NN + GM - 1) / GM;  // 782

    for (int i = 0; i < 3; i++) {
        const float* b1i = b1 + i * DD;
        const float* b2i = b2 + i * DD;
        const unsigned short* Wt1 = Wtall + i * 16384;
        const unsigned short* Wt2 = Wtall + (3 + i) * 16384;

        // g = bf16((1+eps)*xb + sum w*xb[src]); zeroes stats
        gather_kernel<<<(NN + 7) / 8, 256, 0, stream>>>(xb, srcw, rowptr, eps + i, g, stats);

        // t = bf16(relu(g @ W1 + b1))
        mfma_gemm<0><<<gemmGrid, 256, 0, stream>>>(g, Wt1, b1i, t, nullptr);

        // hb = bf16(t @ W2 + b2), + BN stats (fp32)
        mfma_gemm<1><<<gemmGrid, 256, 0, stream>>>(t, Wt2, b2i, hb, stats);

        // xb = bf16(xb + relu(bn(hb))); layer 2 also writes fp32 x
        bn_apply<<<(n4x + 255) / 256, 256, 0, stream>>>(
            hb, stats, gamma + i * DD, beta + i * DD, xb,
            (i < 2) ? (ushort4*)xb : nullptr,
            (i == 2) ? (float4*)x : nullptr);
    }
}

// Round 8
// 387.921 us; speedup vs baseline: 1.1642x; 1.0638x over previous
//
#include <hip/hip_runtime.h>

#define NN 50000
#define NE 800000
#define DD 128
#define D4 32        // float4s per row
#define NBUCK 196    // ceil(NN/256) node buckets
#define CAP 5120     // staging capacity per bucket (mean 4096, ~16 sigma headroom)
#define BIN_EDGES 2048

typedef __attribute__((ext_vector_type(8))) short short8;
typedef __attribute__((ext_vector_type(4))) float f32x4;

__device__ __forceinline__ unsigned short f2bf(float f) {
    unsigned u = __float_as_uint(f);
    unsigned r = u + 0x7FFF + ((u >> 16) & 1);  // RTN-even
    return (unsigned short)(r >> 16);
}
__device__ __forceinline__ float bf2f(unsigned short s) {
    return __uint_as_float(((unsigned)s) << 16);
}

// ---------------- elementwise helpers ----------------

// xb = bf16(x_in)
__global__ void x2b(const float4* __restrict__ xin, ushort4* __restrict__ xb) {
    int i = blockIdx.x * blockDim.x + threadIdx.x;
    if (i >= NN * D4) return;
    float4 v = xin[i];
    ushort4 o;
    o.x = f2bf(v.x); o.y = f2bf(v.y); o.z = f2bf(v.z); o.w = f2bf(v.w);
    xb[i] = o;
}

// ---------------- weight prep: Wt[m][n][k] = bf16(W[m][k][n]) ----------------

__global__ void prep_wt(const float* __restrict__ W1, const float* __restrict__ W2,
                        unsigned short* __restrict__ Wt) {
    int i = blockIdx.x * blockDim.x + threadIdx.x;
    if (i >= 6 * 16384) return;
    int m = i >> 14;
    int r = i & 16383;
    int n = r >> 7;
    int k = r & 127;
    const float* Ws = (m < 3) ? (W1 + m * 16384) : (W2 + (m - 3) * 16384);
    Wt[i] = f2bf(Ws[k * 128 + n]);
}

// ---------------- CSR build: bucket counting sort ----------------
// R6 lesson: line writebacks are per-line regardless of element size; what
// matters is that a line's writers live in ONE block (one XCD L2) within a
// short window. R7 lesson: giant LDS staging (64KB) + tiny grid (98) starves
// occupancy. Fix: per-block direct stores into per-bucket reserved runs --
// each (block,bucket) run is ~80 B, written only by this block, merges in L2.

__global__ void init_bcur(int* __restrict__ bcur) {
    int t = threadIdx.x;
    if (t < NBUCK) bcur[t] = t * CAP;
}

// pass A: bin edges into 196 node-buckets (dst>>8), staging bucket-major.
__global__ void __launch_bounds__(256) bin_pass(const int* __restrict__ ei,
                                                const float* __restrict__ ew,
                                                int* __restrict__ bcur,
                                                int2* __restrict__ staging) {
    __shared__ int cnt[256], base[256], cur[256];
    int tid = threadIdx.x;
    int e0 = blockIdx.x * BIN_EDGES;
    int ne = NE - e0; if (ne > BIN_EDGES) ne = BIN_EDGES;
    cnt[tid] = 0;
    cur[tid] = 0;
    __syncthreads();
    // count (register-cache dst and packed payload; 8 edges/thread)
    int dstv[BIN_EDGES / 256];
    unsigned packv[BIN_EDGES / 256];
#pragma unroll
    for (int j = 0; j < BIN_EDGES / 256; j++) {
        int i = j * 256 + tid;
        dstv[j] = -1;
        if (i < ne) {
            int e = e0 + i;
            int dst = ei[NE + e];
            dstv[j] = dst;
            packv[j] = (((unsigned)ei[e]) << 16) | (unsigned)f2bf(ew[e]);
            atomicAdd(&cnt[dst >> 8], 1);
        }
    }
    __syncthreads();
    // reserve this block's run in each bucket's staging region (1 atomic/bucket)
    if (tid < NBUCK && cnt[tid] > 0) base[tid] = atomicAdd(&bcur[tid], cnt[tid]);
    __syncthreads();
    // place directly: run is block-private and tiny -> stores merge in L2
#pragma unroll
    for (int j = 0; j < BIN_EDGES / 256; j++) {
        int dst = dstv[j];
        if (dst >= 0) {
            int b = dst >> 8;
            int p = atomicAdd(&cur[b], 1);
            staging[base[b] + p] = make_int2((int)packv[j], dst & 255);
        }
    }
}

// exclusive scan of bucket counts -> bucket bases in final CSR
__global__ void scan_buckets(const int* __restrict__ bcur, int* __restrict__ bb2) {
    __shared__ int sh[256];
    int tid = threadIdx.x;
    int c = (tid < NBUCK) ? (bcur[tid] - tid * CAP) : 0;
    sh[tid] = c;
    __syncthreads();
    for (int o = 1; o < 256; o <<= 1) {
        int v = sh[tid];
        int add = (tid >= o) ? sh[tid - o] : 0;
        __syncthreads();
        sh[tid] = v + add;
        __syncthreads();
    }
    if (tid < NBUCK) bb2[tid] = sh[tid] - c;
}

// pass B: one bucket per block; fine-place by dst into LDS, emit rowptr + srcw coalesced.
__global__ void __launch_bounds__(256) place_pass(const int2* __restrict__ staging,
                                                  const int* __restrict__ bcur,
                                                  const int* __restrict__ bb2,
                                                  int* __restrict__ rowptr,
                                                  unsigned* __restrict__ srcw) {
    __shared__ int hist[256], off[256], cur[256];
    __shared__ unsigned outb[CAP];  // 20 KB
    int b = blockIdx.x;
    int tid = threadIdx.x;
    int sbase = b * CAP;
    int nb = bcur[b] - sbase;
    int bucketBase = bb2[b];
    hist[tid] = 0;
    __syncthreads();
    for (int i = tid; i < nb; i += 256) atomicAdd(&hist[staging[sbase + i].y], 1);
    __syncthreads();
    off[tid] = hist[tid];
    __syncthreads();
    for (int o = 1; o < 256; o <<= 1) {
        int v = off[tid];
        int add = (tid >= o) ? off[tid - o] : 0;
        __syncthreads();
        off[tid] = v + add;
        __syncthreads();
    }
    int excl = off[tid] - hist[tid];
    cur[tid] = excl;
    int node = b * 256 + tid;
    if (node < NN) rowptr[node] = bucketBase + excl;
    if (b == 0 && tid == 0) rowptr[NN] = NE;
    __syncthreads();
    for (int i = tid; i < nb; i += 256) {
        int2 r = staging[sbase + i];
        int p = atomicAdd(&cur[r.y], 1);
        outb[p] = (unsigned)r.x;
    }
    __syncthreads();
    for (int i = tid; i < nb; i += 256) srcw[bucketBase + i] = outb[i];
}

// ---- gather + GIN combine: g[n] = bf16((1+eps)*xb[n] + sum_e w_e * xb[src_e]) ----
// 32 lanes per node (8 B of bf16 row each), 8 nodes per 256-block. Zeroes BN stats.

__global__ void __launch_bounds__(256) gather_kernel(
    const unsigned short* __restrict__ xb, const unsigned* __restrict__ srcw,
    const int* __restrict__ rowptr, const float* __restrict__ epsp,
    unsigned short* __restrict__ g, float* __restrict__ stats) {
    if (blockIdx.x == 0) stats[threadIdx.x] = 0.f;  // 256 floats: sum | sumsq
    int node = blockIdx.x * 8 + (threadIdx.x >> 5);
    int lane = threadIdx.x & 31;
    if (node >= NN) return;
    float epsv = 1.0f + *epsp;
    int beg = rowptr[node], end = rowptr[node + 1];
    const ushort4* xb4 = (const ushort4*)xb;
    ushort4 xv = xb4[node * D4 + lane];
    float4 acc = make_float4(bf2f(xv.x) * epsv, bf2f(xv.y) * epsv,
                             bf2f(xv.z) * epsv, bf2f(xv.w) * epsv);
    int i = beg;
    for (; i + 1 < end; i += 2) {
        unsigned sw0 = srcw[i];
        unsigned sw1 = srcw[i + 1];
        ushort4 r0 = xb4[(sw0 >> 16) * D4 + lane];
        ushort4 r1 = xb4[(sw1 >> 16) * D4 + lane];
        float w0 = bf2f((unsigned short)(sw0 & 0xffff));
        float w1 = bf2f((unsigned short)(sw1 & 0xffff));
        acc.x += bf2f(r0.x) * w0; acc.y += bf2f(r0.y) * w0;
        acc.z += bf2f(r0.z) * w0; acc.w += bf2f(r0.w) * w0;
        acc.x += bf2f(r1.x) * w1; acc.y += bf2f(r1.y) * w1;
        acc.z += bf2f(r1.z) * w1; acc.w += bf2f(r1.w) * w1;
    }
    if (i < end) {
        unsigned sw = srcw[i];
        ushort4 r = xb4[(sw >> 16) * D4 + lane];
        float w = bf2f((unsigned short)(sw & 0xffff));
        acc.x += bf2f(r.x) * w; acc.y += bf2f(r.y) * w;
        acc.z += bf2f(r.z) * w; acc.w += bf2f(r.w) * w;
    }
    ushort4 o;
    o.x = f2bf(acc.x); o.y = f2bf(acc.y); o.z = f2bf(acc.z); o.w = f2bf(acc.w);
    ((ushort4*)g)[node * D4 + lane] = o;
}

// ---------------- MFMA GEMM: 64 rows x 128 cols per block, 4 waves ----------------
// MODE 0: out = bf16(relu(A@Wt^T + b))                        (t)
// MODE 1: out = bf16(A@Wt^T + b), BN col sums/sumsq -> stats  (h)

#define GM 64  // rows per block

template <int MODE>
__global__ void __launch_bounds__(256) mfma_gemm(
    const unsigned short* __restrict__ A,   // M x 128 bf16 row-major
    const unsigned short* __restrict__ Wt,  // 128 x 128 bf16, [n][k]
    const float* __restrict__ bias,
    unsigned short* __restrict__ outB, float* __restrict__ stats) {
    __shared__ unsigned short As[GM * 128];  // 16 KB

    int tid = threadIdx.x;
    int wave = tid >> 6;
    int lane = tid & 63;
    int q = lane >> 4;    // quad 0..3
    int ml = lane & 15;
    int r0 = blockIdx.x * GM;

    // stage A tile (zero-pad rows >= NN), 16B-chunk XOR swizzle
#pragma unroll
    for (int i = 0; i < GM / 16; i++) {
        int idx = i * 256 + tid;
        int row = idx >> 4;
        int c = idx & 15;
        float4 v = make_float4(0.f, 0.f, 0.f, 0.f);
        int grow = r0 + row;
        if (grow < NN) v = *(const float4*)(A + grow * DD + c * 8);
        int cs = c ^ (row & 15);
        *(float4*)(&As[row * DD + cs * 8]) = v;
    }

    // B fragments from global (32 KB, L2-resident)
    short8 Bf[2][4];
#pragma unroll
    for (int t = 0; t < 2; t++)
#pragma unroll
        for (int ks = 0; ks < 4; ks++) {
            int n = wave * 32 + t * 16 + ml;
            Bf[t][ks] = *(const short8*)(Wt + n * DD + ks * 32 + q * 8);
        }

    float bvl[2] = {bias[wave * 32 + ml], bias[wave * 32 + 16 + ml]};

    __syncthreads();

    float s[2] = {0.f, 0.f}, s2[2] = {0.f, 0.f};

    for (int rt = 0; rt < GM / 16; rt++) {
        int arow = rt * 16 + ml;
        short8 Af[4];
#pragma unroll
        for (int ks = 0; ks < 4; ks++) {
            int cs = (ks * 4 + q) ^ (arow & 15);
            Af[ks] = *(const short8*)(&As[arow * DD + cs * 8]);
        }
        f32x4 acc[2] = {{0.f, 0.f, 0.f, 0.f}, {0.f, 0.f, 0.f, 0.f}};
#pragma unroll
        for (int ks = 0; ks < 4; ks++) {
            acc[0] = __builtin_amdgcn_mfma_f32_16x16x32_bf16(Af[ks], Bf[0][ks], acc[0], 0, 0, 0);
            acc[1] = __builtin_amdgcn_mfma_f32_16x16x32_bf16(Af[ks], Bf[1][ks], acc[1], 0, 0, 0);
        }
        // epilogue: C/D layout col=lane&15, row=quad*4+reg  [m89-verified]
#pragma unroll
        for (int t = 0; t < 2; t++) {
            int col = wave * 32 + t * 16 + ml;
#pragma unroll
            for (int r = 0; r < 4; r++) {
                int grow = r0 + rt * 16 + q * 4 + r;
                if (grow < NN) {
                    float v = acc[t][r] + bvl[t];
                    if (MODE == 0) {
                        outB[grow * DD + col] = f2bf(fmaxf(v, 0.f));
                    } else {
                        outB[grow * DD + col] = f2bf(v);
                        s[t] += v;
                        s2[t] += v * v;
                    }
                }
            }
        }
    }

    if (MODE == 1) {
#pragma unroll
        for (int t = 0; t < 2; t++) {
            float a = s[t], b = s2[t];
            a += __shfl_xor(a, 16); b += __shfl_xor(b, 16);
            a += __shfl_xor(a, 32); b += __shfl_xor(b, 32);
            if (q == 0) {
                int col = wave * 32 + t * 16 + ml;
                atomicAdd(&stats[col], a);
                atomicAdd(&stats[DD + col], b);
            }
        }
    }
}

// -------- BN apply + ReLU + residual (bf16 chain):
//   xb_out = bf16(xb_in + relu(bn(hb)));  last layer writes fp32 x. --------

__global__ void bn_apply(const unsigned short* __restrict__ hb, const float* __restrict__ stats,
                         const float* __restrict__ gamma, const float* __restrict__ beta,
                         const unsigned short* __restrict__ xbin, ushort4* __restrict__ xbout,
                         float4* __restrict__ xf32) {
    int i = blockIdx.x * blockDim.x + threadIdx.x;
    if (i >= NN * D4) return;
    int c4 = i & 31;
    const float invN = 1.0f / NN;
    float4 s = ((const float4*)stats)[c4];
    float4 s2 = ((const float4*)stats)[D4 + c4];
    float4 mu = make_float4(s.x * invN, s.y * invN, s.z * invN, s.w * invN);
    float4 var = make_float4(s2.x * invN - mu.x * mu.x, s2.y * invN - mu.y * mu.y,
                             s2.z * invN - mu.z * mu.z, s2.w * invN - mu.w * mu.w);
    float4 inv = make_float4(rsqrtf(var.x + 1e-5f), rsqrtf(var.y + 1e-5f),
                             rsqrtf(var.z + 1e-5f), rsqrtf(var.w + 1e-5f));
    float4 g = ((const float4*)gamma)[c4];
    float4 b = ((const float4*)beta)[c4];
    ushort4 hu = ((const ushort4*)hb)[i];
    float4 hv = make_float4(bf2f(hu.x), bf2f(hu.y), bf2f(hu.z), bf2f(hu.w));
    ushort4 xu = ((const ushort4*)xbin)[i];
    float4 xv = make_float4(bf2f(xu.x), bf2f(xu.y), bf2f(xu.z), bf2f(xu.w));
    float4 v = make_float4(fmaxf(g.x * (hv.x - mu.x) * inv.x + b.x, 0.f),
                           fmaxf(g.y * (hv.y - mu.y) * inv.y + b.y, 0.f),
                           fmaxf(g.z * (hv.z - mu.z) * inv.z + b.z, 0.f),
                           fmaxf(g.w * (hv.w - mu.w) * inv.w + b.w, 0.f));
    float4 o = make_float4(xv.x + v.x, xv.y + v.y, xv.z + v.z, xv.w + v.w);
    if (xbout) {
        ushort4 ob;
        ob.x = f2bf(o.x); ob.y = f2bf(o.y); ob.z = f2bf(o.z); ob.w = f2bf(o.w);
        xbout[i] = ob;
    }
    if (xf32) xf32[i] = o;
}

// ---------------- launcher ----------------

extern "C" void kernel_launch(void* const* d_in, const int* in_sizes, int n_in,
                              void* d_out, int out_size, void* d_ws, size_t ws_size,
                              hipStream_t stream) {
    const float* x_in = (const float*)d_in[0];
    const int* ei = (const int*)d_in[1];
    // d_in[2] = edge_attr (unused)
    const float* ew = (const float*)d_in[3];
    const float* W1 = (const float*)d_in[4];
    const float* b1 = (const float*)d_in[5];
    const float* W2 = (const float*)d_in[6];
    const float* b2 = (const float*)d_in[7];
    const float* eps = (const float*)d_in[8];
    const float* gamma = (const float*)d_in[9];
    const float* beta = (const float*)d_in[10];

    float* x = (float*)d_out;  // final fp32 output

    char* ws = (char*)d_ws;
    unsigned short* g = (unsigned short*)ws;               // GIN input bf16 (12.8 MB)
    unsigned short* t = (unsigned short*)(ws + 12800000);  // MLP mid bf16   (12.8 MB)
    unsigned short* hb = (unsigned short*)(ws + 25600000); // MLP out bf16   (12.8 MB)
    int2* staging = (int2*)(ws + 25600000);                // CSR staging 8.03 MB, overlays hb
                                                           // (dead until gemm2 of layer 0)
    unsigned short* xb = (unsigned short*)(ws + 38400000); // running x bf16 (12.8 MB)
    float* stats = (float*)(ws + 51200000);                // 256 floats (sum | sumsq)
    int* rowptr = (int*)(ws + 51201024);                   // 50001 ints
    unsigned short* Wtall = (unsigned short*)(ws + 51401216);  // 6*16384 bf16 (196,608 B)
    unsigned* srcw = (unsigned*)(ws + 51597824);           // 800000 uint (src<<16 | bf16 w)
    int* bcur = (int*)(ws + 54797824);                     // 196 ints (staging cursors)
    int* bb2 = (int*)(ws + 54798848);                      // 196 ints (bucket CSR bases)

    const int n4x = NN * D4;

    // ---- CSR build: bucket counting sort (all global writes block-local runs) ----
    init_bcur<<<1, 256, 0, stream>>>(bcur);
    bin_pass<<<(NE + BIN_EDGES - 1) / BIN_EDGES, 256, 0, stream>>>(ei, ew, bcur, staging);
    scan_buckets<<<1, 256, 0, stream>>>(bcur, bb2);
    place_pass<<<NBUCK, 256, 0, stream>>>(staging, bcur, bb2, rowptr, srcw);

    // weights -> bf16 transposed
    prep_wt<<<(6 * 16384 + 255) / 256, 256, 0, stream>>>(W1, W2, Wtall);

    // bf16 mirror of x for layer-0
    x2b<<<(n4x + 255) / 256, 256, 0, stream>>>((const float4*)x_in, (ushort4*)xb);

    const int gemmGrid = (NN + GM - 1) / GM;  // 782

    for (int i = 0; i < 3; i++) {
        const float* b1i = b1 + i * DD;
        const float* b2i = b2 + i * DD;
        const unsigned short* Wt1 = Wtall + i * 16384;
        const unsigned short* Wt2 = Wtall + (3 + i) * 16384;

        // g = bf16((1+eps)*xb + sum w*xb[src]); zeroes stats
        gather_kernel<<<(NN + 7) / 8, 256, 0, stream>>>(xb, srcw, rowptr, eps + i, g, stats);

        // t = bf16(relu(g @ W1 + b1))
        mfma_gemm<0><<<gemmGrid, 256, 0, stream>>>(g, Wt1, b1i, t, nullptr);

        // hb = bf16(t @ W2 + b2), + BN stats (fp32)
        mfma_gemm<1><<<gemmGrid, 256, 0, stream>>>(t, Wt2, b2i, hb, stats);

        // xb = bf16(xb + relu(bn(hb))); layer 2 also writes fp32 x
        bn_apply<<<(n4x + 255) / 256, 256, 0, stream>>>(
            hb, stats, gamma + i * DD, beta + i * DD, xb,
            (i < 2) ? (ushort4*)xb : nullptr,
            (i == 2) ? (float4*)x : nullptr);
    }
}

// Round 9
// 347.437 us; speedup vs baseline: 1.2998x; 1.1165x over previous
//
#include <hip/hip_runtime.h>

#define NN 50000
#define NE 800000
#define DD 128
#define D4 32        // float4s per row
#define NBUCK 196    // ceil(NN/256) node buckets
#define CAP 5120     // staging capacity per bucket
#define BIN_EDGES 2048

typedef __attribute__((ext_vector_type(8))) short short8;
typedef __attribute__((ext_vector_type(4))) float f32x4;

__device__ __forceinline__ unsigned short f2bf(float f) {
    unsigned u = __float_as_uint(f);
    unsigned r = u + 0x7FFF + ((u >> 16) & 1);  // RTN-even
    return (unsigned short)(r >> 16);
}
__device__ __forceinline__ float bf2f(unsigned short s) {
    return __uint_as_float(((unsigned)s) << 16);
}

// ---------------- fused setup: xb = bf16(x_in) | Wt prep | bcur init ----------------

#define X2B_NB 6250   // NN*D4 / 256
#define WT_NB 384     // 6*16384 / 256

__global__ void setup_kernel(const float4* __restrict__ xin, const float* __restrict__ W1,
                             const float* __restrict__ W2, ushort4* __restrict__ xb,
                             unsigned short* __restrict__ Wt, int* __restrict__ bcur) {
    int bid = blockIdx.x;
    int tid = threadIdx.x;
    if (bid < X2B_NB) {
        int i = bid * 256 + tid;
        float4 v = xin[i];
        ushort4 o;
        o.x = f2bf(v.x); o.y = f2bf(v.y); o.z = f2bf(v.z); o.w = f2bf(v.w);
        xb[i] = o;
    } else if (bid < X2B_NB + WT_NB) {
        int i = (bid - X2B_NB) * 256 + tid;  // Wt[m][n][k] = bf16(W[m][k][n])
        int m = i >> 14;
        int r = i & 16383;
        int n = r >> 7;
        int k = r & 127;
        const float* Ws = (m < 3) ? (W1 + m * 16384) : (W2 + (m - 3) * 16384);
        Wt[i] = f2bf(Ws[k * 128 + n]);
    } else {
        if (tid < NBUCK) bcur[tid] = tid * CAP;
    }
}

// ---------------- CSR build: bucket counting sort ----------------
// R6 lesson: line writebacks are per-line regardless of element size; a line's
// writers must live in ONE block within a short window. R7 lesson: big LDS
// staging + tiny grid starves occupancy. This shape: per-block direct stores
// into per-bucket reserved runs (block-private ~80B runs merge in L2).

__global__ void __launch_bounds__(256) bin_pass(const int* __restrict__ ei,
                                                const float* __restrict__ ew,
                                                int* __restrict__ bcur,
                                                int2* __restrict__ staging) {
    __shared__ int cnt[256], base[256], cur[256];
    int tid = threadIdx.x;
    int e0 = blockIdx.x * BIN_EDGES;
    int ne = NE - e0; if (ne > BIN_EDGES) ne = BIN_EDGES;
    cnt[tid] = 0;
    cur[tid] = 0;
    __syncthreads();
    int dstv[BIN_EDGES / 256];
    unsigned packv[BIN_EDGES / 256];
#pragma unroll
    for (int j = 0; j < BIN_EDGES / 256; j++) {
        int i = j * 256 + tid;
        dstv[j] = -1;
        if (i < ne) {
            int e = e0 + i;
            int dst = ei[NE + e];
            dstv[j] = dst;
            packv[j] = (((unsigned)ei[e]) << 16) | (unsigned)f2bf(ew[e]);
            atomicAdd(&cnt[dst >> 8], 1);
        }
    }
    __syncthreads();
    if (tid < NBUCK && cnt[tid] > 0) base[tid] = atomicAdd(&bcur[tid], cnt[tid]);
    __syncthreads();
#pragma unroll
    for (int j = 0; j < BIN_EDGES / 256; j++) {
        int dst = dstv[j];
        if (dst >= 0) {
            int b = dst >> 8;
            int p = atomicAdd(&cur[b], 1);
            staging[base[b] + p] = make_int2((int)packv[j], dst & 255);
        }
    }
}

__global__ void scan_buckets(const int* __restrict__ bcur, int* __restrict__ bb2) {
    __shared__ int sh[256];
    int tid = threadIdx.x;
    int c = (tid < NBUCK) ? (bcur[tid] - tid * CAP) : 0;
    sh[tid] = c;
    __syncthreads();
    for (int o = 1; o < 256; o <<= 1) {
        int v = sh[tid];
        int add = (tid >= o) ? sh[tid - o] : 0;
        __syncthreads();
        sh[tid] = v + add;
        __syncthreads();
    }
    if (tid < NBUCK) bb2[tid] = sh[tid] - c;
}

__global__ void __launch_bounds__(256) place_pass(const int2* __restrict__ staging,
                                                  const int* __restrict__ bcur,
                                                  const int* __restrict__ bb2,
                                                  int* __restrict__ rowptr,
                                                  unsigned* __restrict__ srcw) {
    __shared__ int hist[256], off[256], cur[256];
    __shared__ unsigned outb[CAP];  // 20 KB
    int b = blockIdx.x;
    int tid = threadIdx.x;
    int sbase = b * CAP;
    int nb = bcur[b] - sbase;
    int bucketBase = bb2[b];
    hist[tid] = 0;
    __syncthreads();
    for (int i = tid; i < nb; i += 256) atomicAdd(&hist[staging[sbase + i].y], 1);
    __syncthreads();
    off[tid] = hist[tid];
    __syncthreads();
    for (int o = 1; o < 256; o <<= 1) {
        int v = off[tid];
        int add = (tid >= o) ? off[tid - o] : 0;
        __syncthreads();
        off[tid] = v + add;
        __syncthreads();
    }
    int excl = off[tid] - hist[tid];
    cur[tid] = excl;
    int node = b * 256 + tid;
    if (node < NN) rowptr[node] = bucketBase + excl;
    if (b == 0 && tid == 0) rowptr[NN] = NE;
    __syncthreads();
    for (int i = tid; i < nb; i += 256) {
        int2 r = staging[sbase + i];
        int p = atomicAdd(&cur[r.y], 1);
        outb[p] = (unsigned)r.x;
    }
    __syncthreads();
    for (int i = tid; i < nb; i += 256) srcw[bucketBase + i] = outb[i];
}

// ---- gather + GIN combine: g[n] = bf16((1+eps)*xb[n] + sum_e w_e * xb[src_e]) ----
// 32 lanes per node, 8 nodes per 256-block, 4 edge-loads in flight. Zeroes BN stats.

__global__ void __launch_bounds__(256) gather_kernel(
    const unsigned short* __restrict__ xb, const unsigned* __restrict__ srcw,
    const int* __restrict__ rowptr, const float* __restrict__ epsp,
    unsigned short* __restrict__ g, float* __restrict__ stats) {
    if (blockIdx.x == 0) stats[threadIdx.x] = 0.f;  // 256 floats: sum | sumsq
    int node = blockIdx.x * 8 + (threadIdx.x >> 5);
    int lane = threadIdx.x & 31;
    if (node >= NN) return;
    float epsv = 1.0f + *epsp;
    int beg = rowptr[node], end = rowptr[node + 1];
    const ushort4* xb4 = (const ushort4*)xb;
    ushort4 xv = xb4[node * D4 + lane];
    float4 acc = make_float4(bf2f(xv.x) * epsv, bf2f(xv.y) * epsv,
                             bf2f(xv.z) * epsv, bf2f(xv.w) * epsv);
    int i = beg;
    for (; i + 3 < end; i += 4) {
        unsigned sw0 = srcw[i], sw1 = srcw[i + 1], sw2 = srcw[i + 2], sw3 = srcw[i + 3];
        ushort4 r0 = xb4[(sw0 >> 16) * D4 + lane];
        ushort4 r1 = xb4[(sw1 >> 16) * D4 + lane];
        ushort4 r2 = xb4[(sw2 >> 16) * D4 + lane];
        ushort4 r3 = xb4[(sw3 >> 16) * D4 + lane];
        float w0 = bf2f((unsigned short)(sw0 & 0xffff));
        float w1 = bf2f((unsigned short)(sw1 & 0xffff));
        float w2 = bf2f((unsigned short)(sw2 & 0xffff));
        float w3 = bf2f((unsigned short)(sw3 & 0xffff));
        acc.x += bf2f(r0.x) * w0; acc.y += bf2f(r0.y) * w0;
        acc.z += bf2f(r0.z) * w0; acc.w += bf2f(r0.w) * w0;
        acc.x += bf2f(r1.x) * w1; acc.y += bf2f(r1.y) * w1;
        acc.z += bf2f(r1.z) * w1; acc.w += bf2f(r1.w) * w1;
        acc.x += bf2f(r2.x) * w2; acc.y += bf2f(r2.y) * w2;
        acc.z += bf2f(r2.z) * w2; acc.w += bf2f(r2.w) * w2;
        acc.x += bf2f(r3.x) * w3; acc.y += bf2f(r3.y) * w3;
        acc.z += bf2f(r3.z) * w3; acc.w += bf2f(r3.w) * w3;
    }
    for (; i < end; i++) {
        unsigned sw = srcw[i];
        ushort4 r = xb4[(sw >> 16) * D4 + lane];
        float w = bf2f((unsigned short)(sw & 0xffff));
        acc.x += bf2f(r.x) * w; acc.y += bf2f(r.y) * w;
        acc.z += bf2f(r.z) * w; acc.w += bf2f(r.w) * w;
    }
    ushort4 o;
    o.x = f2bf(acc.x); o.y = f2bf(acc.y); o.z = f2bf(acc.z); o.w = f2bf(acc.w);
    ((ushort4*)g)[node * D4 + lane] = o;
}

// ---------------- fused MLP: hb = bf16(relu(g@W1t^T+b1) @ W2t^T + b2) + BN stats ----
// 64 rows x 128 cols per block, 4 waves; wave w owns cols [w*32, w*32+32).
// t-tile stays in LDS (swizzled); both weight sets reg-resident.

#define GM 64  // rows per block

__global__ void __launch_bounds__(256) mlp_fused(
    const unsigned short* __restrict__ A,    // g: M x 128 bf16 row-major
    const unsigned short* __restrict__ Wt1,  // 128 x 128 bf16, [n][k]
    const unsigned short* __restrict__ Wt2,
    const float* __restrict__ b1, const float* __restrict__ b2,
    unsigned short* __restrict__ outB, float* __restrict__ stats) {
    __shared__ unsigned short As[GM * 128];  // 16 KB
    __shared__ unsigned short Ts[GM * 128];  // 16 KB

    int tid = threadIdx.x;
    int wave = tid >> 6;
    int lane = tid & 63;
    int q = lane >> 4;    // quad 0..3
    int ml = lane & 15;
    int r0 = blockIdx.x * GM;

    // stage A tile (zero-pad rows >= NN), 16B-chunk XOR swizzle
#pragma unroll
    for (int i = 0; i < GM / 16; i++) {
        int idx = i * 256 + tid;
        int row = idx >> 4;
        int c = idx & 15;
        float4 v = make_float4(0.f, 0.f, 0.f, 0.f);
        int grow = r0 + row;
        if (grow < NN) v = *(const float4*)(A + grow * DD + c * 8);
        int cs = c ^ (row & 15);
        *(float4*)(&As[row * DD + cs * 8]) = v;
    }

    // weight fragments (reg-resident; 32 KB each, L2-hit)
    short8 Bf1[2][4], Bf2[2][4];
#pragma unroll
    for (int t = 0; t < 2; t++)
#pragma unroll
        for (int ks = 0; ks < 4; ks++) {
            int n = wave * 32 + t * 16 + ml;
            Bf1[t][ks] = *(const short8*)(Wt1 + n * DD + ks * 32 + q * 8);
            Bf2[t][ks] = *(const short8*)(Wt2 + n * DD + ks * 32 + q * 8);
        }
    float bvl1[2] = {b1[wave * 32 + ml], b1[wave * 32 + 16 + ml]};
    float bvl2[2] = {b2[wave * 32 + ml], b2[wave * 32 + 16 + ml]};

    __syncthreads();

    // ---- gemm1: t = relu(A @ W1t^T + b1) -> Ts (bf16, swizzled) ----
    for (int rt = 0; rt < GM / 16; rt++) {
        int arow = rt * 16 + ml;
        short8 Af[4];
#pragma unroll
        for (int ks = 0; ks < 4; ks++) {
            int cs = (ks * 4 + q) ^ (arow & 15);
            Af[ks] = *(const short8*)(&As[arow * DD + cs * 8]);
        }
        f32x4 acc[2] = {{0.f, 0.f, 0.f, 0.f}, {0.f, 0.f, 0.f, 0.f}};
#pragma unroll
        for (int ks = 0; ks < 4; ks++) {
            acc[0] = __builtin_amdgcn_mfma_f32_16x16x32_bf16(Af[ks], Bf1[0][ks], acc[0], 0, 0, 0);
            acc[1] = __builtin_amdgcn_mfma_f32_16x16x32_bf16(Af[ks], Bf1[1][ks], acc[1], 0, 0, 0);
        }
        // C/D layout: col=lane&15, row=quad*4+reg [m89-verified]; scatter to Ts
#pragma unroll
        for (int t = 0; t < 2; t++) {
            int col = wave * 32 + t * 16 + ml;
#pragma unroll
            for (int r = 0; r < 4; r++) {
                int lrow = rt * 16 + q * 4 + r;
                unsigned short u = f2bf(fmaxf(acc[t][r] + bvl1[t], 0.f));
                Ts[lrow * DD + ((((col >> 3) ^ (lrow & 15)) << 3) | (col & 7))] = u;
            }
        }
    }
    __syncthreads();

    // ---- gemm2: h = t @ W2t^T + b2 -> global bf16 + BN stats ----
    float s[2] = {0.f, 0.f}, s2[2] = {0.f, 0.f};
    for (int rt = 0; rt < GM / 16; rt++) {
        int arow = rt * 16 + ml;
        short8 Af[4];
#pragma unroll
        for (int ks = 0; ks < 4; ks++) {
            int cs = (ks * 4 + q) ^ (arow & 15);
            Af[ks] = *(const short8*)(&Ts[arow * DD + cs * 8]);
        }
        f32x4 acc[2] = {{0.f, 0.f, 0.f, 0.f}, {0.f, 0.f, 0.f, 0.f}};
#pragma unroll
        for (int ks = 0; ks < 4; ks++) {
            acc[0] = __builtin_amdgcn_mfma_f32_16x16x32_bf16(Af[ks], Bf2[0][ks], acc[0], 0, 0, 0);
            acc[1] = __builtin_amdgcn_mfma_f32_16x16x32_bf16(Af[ks], Bf2[1][ks], acc[1], 0, 0, 0);
        }
#pragma unroll
        for (int t = 0; t < 2; t++) {
            int col = wave * 32 + t * 16 + ml;
#pragma unroll
            for (int r = 0; r < 4; r++) {
                int grow = r0 + rt * 16 + q * 4 + r;
                if (grow < NN) {
                    float v = acc[t][r] + bvl2[t];
                    outB[grow * DD + col] = f2bf(v);
                    s[t] += v;
                    s2[t] += v * v;
                }
            }
        }
    }

#pragma unroll
    for (int t = 0; t < 2; t++) {
        float a = s[t], b = s2[t];
        a += __shfl_xor(a, 16); b += __shfl_xor(b, 16);
        a += __shfl_xor(a, 32); b += __shfl_xor(b, 32);
        if (q == 0) {
            int col = wave * 32 + t * 16 + ml;
            atomicAdd(&stats[col], a);
            atomicAdd(&stats[DD + col], b);
        }
    }
}

// -------- BN apply + ReLU + residual (bf16 chain):
//   xb_out = bf16(xb_in + relu(bn(hb)));  last layer writes fp32 x. --------

__global__ void bn_apply(const unsigned short* __restrict__ hb, const float* __restrict__ stats,
                         const float* __restrict__ gamma, const float* __restrict__ beta,
                         const unsigned short* __restrict__ xbin, ushort4* __restrict__ xbout,
                         float4* __restrict__ xf32) {
    int i = blockIdx.x * blockDim.x + threadIdx.x;
    if (i >= NN * D4) return;
    int c4 = i & 31;
    const float invN = 1.0f / NN;
    float4 s = ((const float4*)stats)[c4];
    float4 s2 = ((const float4*)stats)[D4 + c4];
    float4 mu = make_float4(s.x * invN, s.y * invN, s.z * invN, s.w * invN);
    float4 var = make_float4(s2.x * invN - mu.x * mu.x, s2.y * invN - mu.y * mu.y,
                             s2.z * invN - mu.z * mu.z, s2.w * invN - mu.w * mu.w);
    float4 inv = make_float4(rsqrtf(var.x + 1e-5f), rsqrtf(var.y + 1e-5f),
                             rsqrtf(var.z + 1e-5f), rsqrtf(var.w + 1e-5f));
    float4 g = ((const float4*)gamma)[c4];
    float4 b = ((const float4*)beta)[c4];
    ushort4 hu = ((const ushort4*)hb)[i];
    float4 hv = make_float4(bf2f(hu.x), bf2f(hu.y), bf2f(hu.z), bf2f(hu.w));
    ushort4 xu = ((const ushort4*)xbin)[i];
    float4 xv = make_float4(bf2f(xu.x), bf2f(xu.y), bf2f(xu.z), bf2f(xu.w));
    float4 v = make_float4(fmaxf(g.x * (hv.x - mu.x) * inv.x + b.x, 0.f),
                           fmaxf(g.y * (hv.y - mu.y) * inv.y + b.y, 0.f),
                           fmaxf(g.z * (hv.z - mu.z) * inv.z + b.z, 0.f),
                           fmaxf(g.w * (hv.w - mu.w) * inv.w + b.w, 0.f));
    float4 o = make_float4(xv.x + v.x, xv.y + v.y, xv.z + v.z, xv.w + v.w);
    if (xbout) {
        ushort4 ob;
        ob.x = f2bf(o.x); ob.y = f2bf(o.y); ob.z = f2bf(o.z); ob.w = f2bf(o.w);
        xbout[i] = ob;
    }
    if (xf32) xf32[i] = o;
}

// ---------------- launcher ----------------

extern "C" void kernel_launch(void* const* d_in, const int* in_sizes, int n_in,
                              void* d_out, int out_size, void* d_ws, size_t ws_size,
                              hipStream_t stream) {
    const float* x_in = (const float*)d_in[0];
    const int* ei = (const int*)d_in[1];
    // d_in[2] = edge_attr (unused)
    const float* ew = (const float*)d_in[3];
    const float* W1 = (const float*)d_in[4];
    const float* b1 = (const float*)d_in[5];
    const float* W2 = (const float*)d_in[6];
    const float* b2 = (const float*)d_in[7];
    const float* eps = (const float*)d_in[8];
    const float* gamma = (const float*)d_in[9];
    const float* beta = (const float*)d_in[10];

    float* x = (float*)d_out;  // final fp32 output

    char* ws = (char*)d_ws;
    unsigned short* g = (unsigned short*)ws;               // GIN input bf16 (12.8 MB)
    unsigned short* hb = (unsigned short*)(ws + 12800000); // MLP out bf16   (12.8 MB)
    int2* staging = (int2*)(ws + 12800000);                // CSR staging 8.03 MB, overlays hb
    unsigned short* xb = (unsigned short*)(ws + 25600000); // running x bf16 (12.8 MB)
    float* stats = (float*)(ws + 38400000);                // 256 floats (sum | sumsq)
    int* rowptr = (int*)(ws + 38401024);                   // 50001 ints
    unsigned short* Wtall = (unsigned short*)(ws + 38601216);  // 6*16384 bf16
    unsigned* srcw = (unsigned*)(ws + 38797824);           // 800000 uint (src<<16 | bf16 w)
    int* bcur = (int*)(ws + 41997824);                     // 196 ints (staging cursors)
    int* bb2 = (int*)(ws + 41998848);                      // 196 ints (bucket CSR bases)

    const int n4x = NN * D4;

    // fused setup: xb mirror, weight transpose, bcur init
    setup_kernel<<<X2B_NB + WT_NB + 1, 256, 0, stream>>>(
        (const float4*)x_in, W1, W2, (ushort4*)xb, Wtall, bcur);

    // ---- CSR build: bucket counting sort ----
    bin_pass<<<(NE + BIN_EDGES - 1) / BIN_EDGES, 256, 0, stream>>>(ei, ew, bcur, staging);
    scan_buckets<<<1, 256, 0, stream>>>(bcur, bb2);
    place_pass<<<NBUCK, 256, 0, stream>>>(staging, bcur, bb2, rowptr, srcw);

    const int gemmGrid = (NN + GM - 1) / GM;  // 782

    for (int i = 0; i < 3; i++) {
        const unsigned short* Wt1 = Wtall + i * 16384;
        const unsigned short* Wt2 = Wtall + (3 + i) * 16384;

        // g = bf16((1+eps)*xb + sum w*xb[src]); zeroes stats
        gather_kernel<<<(NN + 7) / 8, 256, 0, stream>>>(xb, srcw, rowptr, eps + i, g, stats);

        // hb = bf16(relu(g@W1+b1)@W2+b2), + BN stats
        mlp_fused<<<gemmGrid, 256, 0, stream>>>(g, Wt1, Wt2, b1 + i * DD, b2 + i * DD, hb, stats);

        // xb = bf16(xb + relu(bn(hb))); layer 2 also writes fp32 x
        bn_apply<<<(n4x + 255) / 256, 256, 0, stream>>>(
            hb, stats, gamma + i * DD, beta + i * DD, xb,
            (i < 2) ? (ushort4*)xb : nullptr,
            (i == 2) ? (float4*)x : nullptr);
    }
}